// Round 1
// baseline (4376.363 us; speedup 1.0000x reference)
//
#include <hip/hip_runtime.h>
#include <hip/hip_bf16.h>

#define N_EMBD 1024
#define N_HEAD 16
#define HEAD_DIM 64
#define BATCH 8
#define SEQ_T 1024
#define SEQ_I 257

// ---------------------------------------------------------------------------
// LayerNorm: one block per row of 1024 floats. 256 threads * float4.
// ---------------------------------------------------------------------------
__global__ __launch_bounds__(256)
void ln_kernel(const float* __restrict__ in, const float* __restrict__ gamma,
               const float* __restrict__ beta, float* __restrict__ out)
{
    const int row = blockIdx.x;
    const int tid = threadIdx.x;
    const float4 v = *(const float4*)(in + (size_t)row * N_EMBD + tid * 4);
    float s  = v.x + v.y + v.z + v.w;
    float ss = v.x*v.x + v.y*v.y + v.z*v.z + v.w*v.w;
    #pragma unroll
    for (int off = 32; off >= 1; off >>= 1) {
        s  += __shfl_down(s,  off);
        ss += __shfl_down(ss, off);
    }
    __shared__ float rs[4], rss[4];
    const int wid = tid >> 6, lane = tid & 63;
    if (lane == 0) { rs[wid] = s; rss[wid] = ss; }
    __syncthreads();
    s  = rs[0] + rs[1] + rs[2] + rs[3];
    ss = rss[0] + rss[1] + rss[2] + rss[3];
    const float mean = s * (1.0f / N_EMBD);
    const float var  = ss * (1.0f / N_EMBD) - mean * mean;
    const float rstd = rsqrtf(var + 1e-5f);
    const float4 g = *(const float4*)(gamma + tid * 4);
    const float4 b = *(const float4*)(beta  + tid * 4);
    float4 o;
    o.x = (v.x - mean) * rstd * g.x + b.x;
    o.y = (v.y - mean) * rstd * g.y + b.y;
    o.z = (v.z - mean) * rstd * g.z + b.z;
    o.w = (v.w - mean) * rstd * g.w + b.w;
    *(float4*)(out + (size_t)row * N_EMBD + tid * 4) = o;
}

// ---------------------------------------------------------------------------
// GELU (tanh approximation), matches jax.nn.gelu(approximate=True)
// ---------------------------------------------------------------------------
__device__ __forceinline__ float gelu_tanh(float u)
{
    float z = 0.7978845608028654f * (u + 0.044715f * u * u * u);
    z = fmaxf(z, -15.0f);                 // avoid inf/inf; tanh(-15) == -1 in fp32
    const float e = __expf(-2.0f * z);
    const float t = (1.0f - e) / (1.0f + e);
    return 0.5f * u * (1.0f + t);
}

// ---------------------------------------------------------------------------
// fp32 GEMM: out[M,N] = A[M,K] @ W[K,N] + bias  (+res) (gelu)
// 128x128 tile, BK=8, 256 threads, 8x8 micro-tile as 2x2 of 4x4.
// EPI: 0 = bias, 1 = bias + residual add, 2 = bias + gelu
// ---------------------------------------------------------------------------
template<int EPI>
__global__ __launch_bounds__(256, 4)
void gemm_kernel(const float* __restrict__ A, const float* __restrict__ W,
                 const float* __restrict__ bias, const float* __restrict__ res,
                 float* __restrict__ out, int M, int N, int K)
{
    __shared__ float As[8][128];
    __shared__ float Bs[8][128];
    const int tid = threadIdx.x;
    const int bm = blockIdx.y * 128;
    const int bn = blockIdx.x * 128;
    const int tx = tid & 15, ty = tid >> 4;

    float acc[2][4][2][4] = {};

    const int ar = tid >> 1;            // 0..127 (row within A tile)
    const int ak = (tid & 1) * 4;       // 0 or 4 (k within tile)
    const int br = tid >> 5;            // 0..7   (k row of B tile)
    const int bc = (tid & 31) * 4;      // 0..124 (col within B tile)
    const bool avalid = (bm + ar) < M;
    const float* Aptr = A + (size_t)(bm + ar) * K + ak;
    const float* Wptr = W + (size_t)br * N + bn + bc;

    for (int k0 = 0; k0 < K; k0 += 8) {
        float4 av = make_float4(0.f, 0.f, 0.f, 0.f);
        if (avalid) av = *(const float4*)(Aptr + k0);
        const float4 bv = *(const float4*)(Wptr + (size_t)k0 * N);
        __syncthreads();   // previous tile's reads done
        As[ak + 0][ar] = av.x;
        As[ak + 1][ar] = av.y;
        As[ak + 2][ar] = av.z;
        As[ak + 3][ar] = av.w;
        *(float4*)&Bs[br][bc] = bv;
        __syncthreads();
        #pragma unroll
        for (int kk = 0; kk < 8; ++kk) {
            float a[8], b[8];
            #pragma unroll
            for (int i = 0; i < 4; ++i) {
                a[i]     = As[kk][ty * 4 + i];
                a[4 + i] = As[kk][64 + ty * 4 + i];
                b[i]     = Bs[kk][tx * 4 + i];
                b[4 + i] = Bs[kk][64 + tx * 4 + i];
            }
            #pragma unroll
            for (int ih = 0; ih < 2; ++ih)
                #pragma unroll
                for (int i = 0; i < 4; ++i)
                    #pragma unroll
                    for (int jh = 0; jh < 2; ++jh)
                        #pragma unroll
                        for (int j = 0; j < 4; ++j)
                            acc[ih][i][jh][j] += a[ih * 4 + i] * b[jh * 4 + j];
        }
    }

    #pragma unroll
    for (int ih = 0; ih < 2; ++ih) {
        #pragma unroll
        for (int i = 0; i < 4; ++i) {
            const int m = bm + ih * 64 + ty * 4 + i;
            if (m >= M) continue;
            #pragma unroll
            for (int jh = 0; jh < 2; ++jh) {
                const int n0 = bn + jh * 64 + tx * 4;
                const float4 bb = *(const float4*)(bias + n0);
                const float* bbp = &bb.x;
                float vals[4];
                #pragma unroll
                for (int j = 0; j < 4; ++j)
                    vals[j] = acc[ih][i][jh][j] + bbp[j];
                if (EPI == 1) {
                    const float4 rr = *(const float4*)(res + (size_t)m * N + n0);
                    const float* rrp = &rr.x;
                    #pragma unroll
                    for (int j = 0; j < 4; ++j) vals[j] += rrp[j];
                }
                if (EPI == 2) {
                    #pragma unroll
                    for (int j = 0; j < 4; ++j) vals[j] = gelu_tanh(vals[j]);
                }
                float4 ov;
                ov.x = vals[0]; ov.y = vals[1]; ov.z = vals[2]; ov.w = vals[3];
                *(float4*)(out + (size_t)m * N + n0) = ov;
            }
        }
    }
}

// ---------------------------------------------------------------------------
// Attention: one thread per q row (256 q rows per block), K/V tiles of 64
// staged in LDS, online softmax in registers. Template CAUSAL.
// Qm: row (b*1024+t)*qStride + h*64.  Km/Vm: row (b*nKeys+s)*kStride + h*64.
// out: [B,T,1024] at (b*1024+t)*1024 + h*64.
// ---------------------------------------------------------------------------
template<bool CAUSAL>
__global__ __launch_bounds__(256, 2)
void attn_kernel(const float* __restrict__ Qm, const float* __restrict__ Km,
                 const float* __restrict__ Vm, float* __restrict__ out,
                 int qStride, int kStride, int nKeys)
{
    __shared__ float Ks[64][64];
    __shared__ float Vs[64][64];
    const int tid = threadIdx.x;
    const int qt  = blockIdx.x;          // q tile (256 rows each)
    const int bh  = blockIdx.y;          // 0..127
    const int b   = bh >> 4, h = bh & 15;
    const int t   = qt * 256 + tid;

    float q[64], o[64];
    const float* qrow = Qm + (size_t)(b * SEQ_T + t) * qStride + h * HEAD_DIM;
    #pragma unroll
    for (int d = 0; d < 64; d += 4) {
        const float4 v = *(const float4*)(qrow + d);
        q[d]   = v.x * 0.125f;   // 1/sqrt(64)
        q[d+1] = v.y * 0.125f;
        q[d+2] = v.z * 0.125f;
        q[d+3] = v.w * 0.125f;
    }
    #pragma unroll
    for (int d = 0; d < 64; ++d) o[d] = 0.f;
    float m = -1e30f, l = 0.f;

    const int myKeys = CAUSAL ? (t + 1) : nKeys;
    const int ntiles = CAUSAL ? (qt * 4 + 4) : ((nKeys + 63) >> 6);

    for (int st = 0; st < ntiles; ++st) {
        __syncthreads();
        const int base = st * 64;
        const int tileKeys = min(64, nKeys - base);
        #pragma unroll
        for (int rep = 0; rep < 4; ++rep) {
            const int s  = rep * 16 + (tid >> 4);
            const int d4 = (tid & 15) * 4;
            if (s < tileKeys) {
                const size_t krow = (size_t)(b * nKeys + base + s) * kStride + h * HEAD_DIM + d4;
                *(float4*)&Ks[s][d4] = *(const float4*)(Km + krow);
                *(float4*)&Vs[s][d4] = *(const float4*)(Vm + krow);
            }
        }
        __syncthreads();
        const int smax = min(tileKeys, myKeys - base);
        for (int s = 0; s < smax; ++s) {
            float sc = 0.f;
            #pragma unroll
            for (int d = 0; d < 64; ++d) sc += q[d] * Ks[s][d];
            if (sc > m) {
                const float f = __expf(m - sc);
                l *= f;
                #pragma unroll
                for (int d = 0; d < 64; ++d) o[d] *= f;
                m = sc;
            }
            const float p = __expf(sc - m);
            l += p;
            #pragma unroll
            for (int d = 0; d < 64; ++d) o[d] += p * Vs[s][d];
        }
    }

    const float inv = 1.0f / l;
    float* orow = out + (size_t)(b * SEQ_T + t) * N_EMBD + h * HEAD_DIM;
    #pragma unroll
    for (int d = 0; d < 64; d += 4) {
        float4 ov;
        ov.x = o[d] * inv; ov.y = o[d+1] * inv; ov.z = o[d+2] * inv; ov.w = o[d+3] * inv;
        *(float4*)(orow + d) = ov;
    }
}

// ---------------------------------------------------------------------------
// launch
// ---------------------------------------------------------------------------
extern "C" void kernel_launch(void* const* d_in, const int* in_sizes, int n_in,
                              void* d_out, int out_size, void* d_ws, size_t ws_size,
                              hipStream_t stream)
{
    const float* x     = (const float*)d_in[0];
    const float* enc   = (const float*)d_in[1];
    const float* ln1_g = (const float*)d_in[2];
    const float* ln1_b = (const float*)d_in[3];
    const float* ln2_g = (const float*)d_in[4];
    const float* ln2_b = (const float*)d_in[5];
    const float* ln3_g = (const float*)d_in[6];
    const float* ln3_b = (const float*)d_in[7];
    const float* w_qkv = (const float*)d_in[8];
    const float* b_qkv = (const float*)d_in[9];
    const float* w_ao  = (const float*)d_in[10];
    const float* b_ao  = (const float*)d_in[11];
    const float* w_q   = (const float*)d_in[12];
    const float* b_q   = (const float*)d_in[13];
    const float* w_kv  = (const float*)d_in[14];
    const float* b_kv  = (const float*)d_in[15];
    const float* w_co  = (const float*)d_in[16];
    const float* b_co  = (const float*)d_in[17];
    const float* w_fc  = (const float*)d_in[18];
    const float* b_fc  = (const float*)d_in[19];
    const float* w_mo  = (const float*)d_in[20];
    const float* b_mo  = (const float*)d_in[21];
    float* outp = (float*)d_out;

    // workspace layout (floats):
    // R0 [0 .. 33554432): qkv (25165824) + kv (@25165824, 4210688); later h (33554432)
    // R1 [33554432): y1/y2/cross_out/y3 (8388608)
    // R2 [41943040): attn_out / q / y3' (8388608)
    // R3 [50331648): x1 (8388608)
    // R4 [58720256): x2 (8388608)  -> total 67108864 floats = 256 MB
    float* ws   = (float*)d_ws;
    float* qkvb = ws;
    float* kvb  = ws + 25165824;
    float* hb   = ws;
    float* yb   = ws + 33554432;
    float* qb   = ws + 41943040;
    float* x1b  = ws + 50331648;
    float* x2b  = ws + 58720256;

    const int ROWS = BATCH * SEQ_T;          // 8192
    const int EROWS = BATCH * SEQ_I;         // 2056

    // 1. y1 = LN(x)
    ln_kernel<<<ROWS, 256, 0, stream>>>(x, ln1_g, ln1_b, yb);
    // 2. qkv = y1 @ w_qkv + b_qkv           [8192, 3072]
    gemm_kernel<0><<<dim3(3072 / 128, ROWS / 128), 256, 0, stream>>>(
        yb, w_qkv, b_qkv, nullptr, qkvb, ROWS, 3072, 1024);
    // 3. self attention (causal) -> attn_out [8192, 1024]
    attn_kernel<true><<<dim3(SEQ_T / 256, BATCH * N_HEAD), 256, 0, stream>>>(
        qkvb, qkvb + 1024, qkvb + 2048, qb, 3072, 3072, SEQ_T);
    // 4. x1 = x + attn_out @ w_ao + b_ao
    gemm_kernel<1><<<dim3(1024 / 128, ROWS / 128), 256, 0, stream>>>(
        qb, w_ao, b_ao, x, x1b, ROWS, 1024, 1024);
    // 5. y2 = LN(x1)
    ln_kernel<<<ROWS, 256, 0, stream>>>(x1b, ln2_g, ln2_b, yb);
    // 6. q = y2 @ w_q + b_q
    gemm_kernel<0><<<dim3(1024 / 128, ROWS / 128), 256, 0, stream>>>(
        yb, w_q, b_q, nullptr, qb, ROWS, 1024, 1024);
    // 7. kv = enc @ w_kv + b_kv             [2056, 2048]
    gemm_kernel<0><<<dim3(2048 / 128, (EROWS + 127) / 128), 256, 0, stream>>>(
        enc, w_kv, b_kv, nullptr, kvb, EROWS, 2048, 1024);
    // 8. cross attention -> yb (y2 dead)
    attn_kernel<false><<<dim3(SEQ_T / 256, BATCH * N_HEAD), 256, 0, stream>>>(
        qb, kvb, kvb + 1024, yb, 1024, 2048, SEQ_I);
    // 9. x2 = x1 + cross_out @ w_co + b_co
    gemm_kernel<1><<<dim3(1024 / 128, ROWS / 128), 256, 0, stream>>>(
        yb, w_co, b_co, x1b, x2b, ROWS, 1024, 1024);
    // 10. y3 = LN(x2) -> qb (q dead)
    ln_kernel<<<ROWS, 256, 0, stream>>>(x2b, ln3_g, ln3_b, qb);
    // 11. h = gelu(y3 @ w_fc + b_fc)        [8192, 4096]
    gemm_kernel<2><<<dim3(4096 / 128, ROWS / 128), 256, 0, stream>>>(
        qb, w_fc, b_fc, nullptr, hb, ROWS, 4096, 1024);
    // 12. out = x2 + h @ w_mo + b_mo
    gemm_kernel<1><<<dim3(1024 / 128, ROWS / 128), 256, 0, stream>>>(
        hb, w_mo, b_mo, x2b, outp, ROWS, 1024, 4096);
}

// Round 5
// 2092.880 us; speedup vs baseline: 2.0911x; 2.0911x over previous
//
#include <hip/hip_runtime.h>
#include <hip/hip_bf16.h>

#define N_EMBD 1024
#define N_HEAD 16
#define HEAD_DIM 64
#define BATCH 8
#define SEQ_T 1024
#define SEQ_I 257

typedef __attribute__((ext_vector_type(8))) short short8_t;
typedef __attribute__((ext_vector_type(4))) float f32x4;

// f32 -> bf16 RNE
static __device__ __forceinline__ unsigned short f2b(float f)
{
    unsigned int u = __float_as_uint(f);
    u = (u + 0x7fffu + ((u >> 16) & 1u)) >> 16;
    return (unsigned short)u;
}
static __device__ __forceinline__ float b2f_lo(unsigned int u) { return __uint_as_float(u << 16); }
static __device__ __forceinline__ float b2f_hi(unsigned int u) { return __uint_as_float(u & 0xffff0000u); }

__device__ __forceinline__ float gelu_tanh(float u)
{
    float z = 0.7978845608028654f * (u + 0.044715f * u * u * u);
    z = fmaxf(z, -15.0f);
    const float e = __expf(-2.0f * z);
    const float t = (1.0f - e) / (1.0f + e);
    return 0.5f * u * (1.0f + t);
}

// ---------------------------------------------------------------------------
// Weight transpose+cast: W[K,N] f32 -> WT[N,K] bf16
// ---------------------------------------------------------------------------
__global__ __launch_bounds__(256)
void wcast_t(const float* __restrict__ W, short* __restrict__ WT, int K, int N)
{
    __shared__ float t[32][33];
    const int n0 = blockIdx.x * 32, k0 = blockIdx.y * 32;
    const int c = threadIdx.x & 31, r4 = (threadIdx.x >> 5) * 4;
    #pragma unroll
    for (int i = 0; i < 4; ++i)
        t[r4 + i][c] = W[(size_t)(k0 + r4 + i) * N + n0 + c];
    __syncthreads();
    #pragma unroll
    for (int i = 0; i < 4; ++i)
        WT[(size_t)(n0 + r4 + i) * K + k0 + c] = (short)f2b(t[c][r4 + i]);
}

// elementwise f32 -> bf16 (enc), 4 elems/thread
__global__ __launch_bounds__(256)
void cast_bf16(const float* __restrict__ in, short* __restrict__ out)
{
    const int i = blockIdx.x * 256 + threadIdx.x;
    const float4 v = ((const float4*)in)[i];
    unsigned int w0 = (unsigned int)f2b(v.x) | ((unsigned int)f2b(v.y) << 16);
    unsigned int w1 = (unsigned int)f2b(v.z) | ((unsigned int)f2b(v.w) << 16);
    ((uint2*)out)[i] = make_uint2(w0, w1);
}

// ---------------------------------------------------------------------------
// LayerNorm: f32 in -> bf16 out. one block per row of 1024.
// ---------------------------------------------------------------------------
__global__ __launch_bounds__(256)
void ln_bf16(const float* __restrict__ in, const float* __restrict__ gamma,
             const float* __restrict__ beta, short* __restrict__ out)
{
    const int row = blockIdx.x;
    const int tid = threadIdx.x;
    const float4 v = *(const float4*)(in + (size_t)row * N_EMBD + tid * 4);
    float s  = v.x + v.y + v.z + v.w;
    float ss = v.x*v.x + v.y*v.y + v.z*v.z + v.w*v.w;
    #pragma unroll
    for (int off = 32; off >= 1; off >>= 1) {
        s  += __shfl_down(s,  off);
        ss += __shfl_down(ss, off);
    }
    __shared__ float rs[4], rss[4];
    const int wid = tid >> 6, lane = tid & 63;
    if (lane == 0) { rs[wid] = s; rss[wid] = ss; }
    __syncthreads();
    s  = rs[0] + rs[1] + rs[2] + rs[3];
    ss = rss[0] + rss[1] + rss[2] + rss[3];
    const float mean = s * (1.0f / N_EMBD);
    const float var  = ss * (1.0f / N_EMBD) - mean * mean;
    const float rstd = rsqrtf(var + 1e-5f);
    const float4 g = *(const float4*)(gamma + tid * 4);
    const float4 b = *(const float4*)(beta  + tid * 4);
    float o0 = (v.x - mean) * rstd * g.x + b.x;
    float o1 = (v.y - mean) * rstd * g.y + b.y;
    float o2 = (v.z - mean) * rstd * g.z + b.z;
    float o3 = (v.w - mean) * rstd * g.w + b.w;
    unsigned int w0 = (unsigned int)f2b(o0) | ((unsigned int)f2b(o1) << 16);
    unsigned int w1 = (unsigned int)f2b(o2) | ((unsigned int)f2b(o3) << 16);
    ((uint2*)(out + (size_t)row * N_EMBD))[tid] = make_uint2(w0, w1);
}

// ---------------------------------------------------------------------------
// bf16 MFMA GEMM: C[M,N] = A[M,K](bf16) @ WT[N,K](bf16)^T + bias (+res) (gelu)
// 128x128 tile, BK=32, 4 waves (2x2 of 64x64), 16x16x32 MFMA, 4x4 frags/wave.
// LDS XOR swizzle: 16B slot s of row r holds global k-group (s ^ ((r>>1)&3)).
// EPI: 0 = bias -> bf16 out; 1 = bias + res(f32) -> f32 out; 2 = bias+gelu -> bf16
// ---------------------------------------------------------------------------
template<int EPI>
__global__ __launch_bounds__(256, 2)
void gemm_mfma(const short* __restrict__ A, const short* __restrict__ WT,
               const float* __restrict__ bias, const float* __restrict__ res,
               void* __restrict__ outv, int M, int N, int K, int lda)
{
    __shared__ short As[128 * 32];
    __shared__ short Bs[128 * 32];
    const int tid  = threadIdx.x;
    const int bm   = blockIdx.y * 128;
    const int bn   = blockIdx.x * 128;
    const int lane = tid & 63;
    const int wid  = tid >> 6;
    const int wr   = (wid >> 1) * 64;
    const int wc   = (wid & 1) * 64;
    const int fr   = lane & 15;
    const int kg   = lane >> 4;

    // staging: 2 passes x 256 threads x 16B for each of A,B
    const int idx0 = tid;              // rows 0..63
    const int idx1 = 256 + tid;        // rows 64..127
    const int r0 = idx0 >> 2, g0 = (idx0 & 3) ^ ((r0 >> 1) & 3);
    const int r1 = idx1 >> 2, g1 = (idx1 & 3) ^ ((r1 >> 1) & 3);
    const short* aSrc0 = A  + (size_t)min(bm + r0, M - 1) * lda + g0 * 8;
    const short* aSrc1 = A  + (size_t)min(bm + r1, M - 1) * lda + g1 * 8;
    const short* bSrc0 = WT + (size_t)(bn + r0) * K + g0 * 8;
    const short* bSrc1 = WT + (size_t)(bn + r1) * K + g1 * 8;
    const int dst0 = (tid & ~63) * 16;           // byte offset, pass 0
    const int dst1 = (256 + (tid & ~63)) * 16;   // byte offset, pass 1

    // frag read offsets (in shorts), constant over k-steps
    int offA[4], offB[4];
    #pragma unroll
    for (int f = 0; f < 4; ++f) {
        const int ra = wr + f * 16 + fr;
        offA[f] = ra * 32 + ((kg ^ ((ra >> 1) & 3)) * 8);
        const int rb = wc + f * 16 + fr;
        offB[f] = rb * 32 + ((kg ^ ((rb >> 1) & 3)) * 8);
    }

    f32x4 acc[4][4];
    #pragma unroll
    for (int i = 0; i < 4; ++i)
        #pragma unroll
        for (int j = 0; j < 4; ++j)
            acc[i][j] = (f32x4){0.f, 0.f, 0.f, 0.f};

    for (int k0 = 0; k0 < K; k0 += 32) {
        __builtin_amdgcn_global_load_lds(
            (const __attribute__((address_space(1))) void*)(aSrc0 + k0),
            (__attribute__((address_space(3))) void*)((char*)As + dst0), 16, 0, 0);
        __builtin_amdgcn_global_load_lds(
            (const __attribute__((address_space(1))) void*)(aSrc1 + k0),
            (__attribute__((address_space(3))) void*)((char*)As + dst1), 16, 0, 0);
        __builtin_amdgcn_global_load_lds(
            (const __attribute__((address_space(1))) void*)(bSrc0 + k0),
            (__attribute__((address_space(3))) void*)((char*)Bs + dst0), 16, 0, 0);
        __builtin_amdgcn_global_load_lds(
            (const __attribute__((address_space(1))) void*)(bSrc1 + k0),
            (__attribute__((address_space(3))) void*)((char*)Bs + dst1), 16, 0, 0);
        __syncthreads();
        short8_t af[4], bf[4];
        #pragma unroll
        for (int f = 0; f < 4; ++f) {
            af[f] = *(const short8_t*)(As + offA[f]);
            bf[f] = *(const short8_t*)(Bs + offB[f]);
        }
        #pragma unroll
        for (int i = 0; i < 4; ++i)
            #pragma unroll
            for (int j = 0; j < 4; ++j)
                acc[i][j] = __builtin_amdgcn_mfma_f32_16x16x32_bf16(af[i], bf[j], acc[i][j], 0, 0, 0);
        __syncthreads();
    }

    // epilogue: C/D frag: n = lane&15, m = (lane>>4)*4 + r
    #pragma unroll
    for (int i = 0; i < 4; ++i) {
        #pragma unroll
        for (int r = 0; r < 4; ++r) {
            const int m = bm + wr + i * 16 + kg * 4 + r;
            if (m >= M) continue;
            #pragma unroll
            for (int j = 0; j < 4; ++j) {
                const int n = bn + wc + j * 16 + fr;
                float v = acc[i][j][r] + bias[n];
                if (EPI == 1) v += res[(size_t)m * N + n];
                if (EPI == 2) v = gelu_tanh(v);
                if (EPI == 1) ((float*)outv)[(size_t)m * N + n] = v;
                else          ((short*)outv)[(size_t)m * N + n] = (short)f2b(v);
            }
        }
    }
}

// ---------------------------------------------------------------------------
// Attention, scalar-pipe K/V: one thread per q row. K/V rows are wave-uniform
// -> scalar loads (SMEM) + SALU bf16 unpack; FMA with SGPR operand. No LDS.
// Qm/Km/Vm bf16 (as short*). out bf16. Causal: heavy q-tiles dispatched first.
// ---------------------------------------------------------------------------
template<bool CAUSAL>
__global__ __launch_bounds__(256)
void attn_scalar(const short* __restrict__ Qm, const short* __restrict__ Km,
                 const short* __restrict__ Vm, short* __restrict__ out,
                 int qStride, int kStride, int kRows)
{
    const int tid = threadIdx.x;
    const int bid = blockIdx.x;
    const int qt  = CAUSAL ? (3 - (bid >> 7)) : (bid >> 7);
    const int bh  = bid & 127;
    const int b   = bh >> 4, h = bh & 15;
    const int t   = qt * 256 + tid;

    float q[64], o[64];
    {
        const uint4* Qr = (const uint4*)(Qm + (size_t)(b * SEQ_T + t) * qStride + h * HEAD_DIM);
        #pragma unroll
        for (int i = 0; i < 8; ++i) {
            const uint4 u = Qr[i];
            q[8*i+0] = b2f_lo(u.x) * 0.125f; q[8*i+1] = b2f_hi(u.x) * 0.125f;
            q[8*i+2] = b2f_lo(u.y) * 0.125f; q[8*i+3] = b2f_hi(u.y) * 0.125f;
            q[8*i+4] = b2f_lo(u.z) * 0.125f; q[8*i+5] = b2f_hi(u.z) * 0.125f;
            q[8*i+6] = b2f_lo(u.w) * 0.125f; q[8*i+7] = b2f_hi(u.w) * 0.125f;
        }
    }
    #pragma unroll
    for (int d = 0; d < 64; ++d) o[d] = 0.f;
    float m = -1e30f, l = 0.f;

    const unsigned int* Kb = (const unsigned int*)(Km + (size_t)b * kRows * kStride + h * HEAD_DIM);
    const unsigned int* Vb = (const unsigned int*)(Vm + (size_t)b * kRows * kStride + h * HEAD_DIM);
    const int kstr = kStride >> 1;
    const int send = CAUSAL ? (__builtin_amdgcn_readfirstlane(t | 63) + 1) : kRows;

    for (int s = 0; s < send; ++s) {
        const unsigned int* Kr = Kb + (size_t)s * kstr;
        float ps[8] = {0.f,0.f,0.f,0.f,0.f,0.f,0.f,0.f};
        #pragma unroll
        for (int i = 0; i < 32; ++i) {
            const unsigned int u = Kr[i];
            ps[(2*i)   & 7] = fmaf(q[2*i],   b2f_lo(u), ps[(2*i)   & 7]);
            ps[(2*i+1) & 7] = fmaf(q[2*i+1], b2f_hi(u), ps[(2*i+1) & 7]);
        }
        float sc = ((ps[0]+ps[1]) + (ps[2]+ps[3])) + ((ps[4]+ps[5]) + (ps[6]+ps[7]));
        if (CAUSAL && s > t) sc = -1e30f;
        if (__ballot(sc > m)) {
            const float mn = fmaxf(m, sc);
            const float f = __expf(m - mn);
            l *= f;
            #pragma unroll
            for (int d = 0; d < 64; ++d) o[d] *= f;
            m = mn;
        }
        const float p = __expf(sc - m);
        l += p;
        const unsigned int* Vr = Vb + (size_t)s * kstr;
        #pragma unroll
        for (int i = 0; i < 32; ++i) {
            const unsigned int u = Vr[i];
            o[2*i]   = fmaf(p, b2f_lo(u), o[2*i]);
            o[2*i+1] = fmaf(p, b2f_hi(u), o[2*i+1]);
        }
    }

    const float inv = 1.0f / l;
    unsigned int* orow = (unsigned int*)(out + (size_t)(b * SEQ_T + t) * N_EMBD + h * HEAD_DIM);
    #pragma unroll
    for (int i = 0; i < 32; ++i)
        orow[i] = (unsigned int)f2b(o[2*i] * inv) | ((unsigned int)f2b(o[2*i+1] * inv) << 16);
}

// ---------------------------------------------------------------------------
// launch
// ---------------------------------------------------------------------------
extern "C" void kernel_launch(void* const* d_in, const int* in_sizes, int n_in,
                              void* d_out, int out_size, void* d_ws, size_t ws_size,
                              hipStream_t stream)
{
    const float* x     = (const float*)d_in[0];
    const float* enc   = (const float*)d_in[1];
    const float* ln1_g = (const float*)d_in[2];
    const float* ln1_b = (const float*)d_in[3];
    const float* ln2_g = (const float*)d_in[4];
    const float* ln2_b = (const float*)d_in[5];
    const float* ln3_g = (const float*)d_in[6];
    const float* ln3_b = (const float*)d_in[7];
    const float* w_qkv = (const float*)d_in[8];
    const float* b_qkv = (const float*)d_in[9];
    const float* w_ao  = (const float*)d_in[10];
    const float* b_ao  = (const float*)d_in[11];
    const float* w_q   = (const float*)d_in[12];
    const float* b_q   = (const float*)d_in[13];
    const float* w_kv  = (const float*)d_in[14];
    const float* b_kv  = (const float*)d_in[15];
    const float* w_co  = (const float*)d_in[16];
    const float* b_co  = (const float*)d_in[17];
    const float* w_fc  = (const float*)d_in[18];
    const float* b_fc  = (const float*)d_in[19];
    const float* w_mo  = (const float*)d_in[20];
    const float* b_mo  = (const float*)d_in[21];
    float* outp = (float*)d_out;

    // workspace layout
    short* wt_qkv = (short*)d_ws;
    short* wt_ao  = wt_qkv + 3145728;
    short* wt_q   = wt_ao  + 1048576;
    short* wt_kv  = wt_q   + 1048576;
    short* wt_co  = wt_kv  + 2097152;
    short* wt_fc  = wt_co  + 1048576;
    short* wt_mo  = wt_fc  + 4194304;
    short* enc_b  = wt_mo  + 4194304;                 // 2,105,344 bf16
    short* y_b    = enc_b  + 2105344;                 // 8,388,608 bf16
    short* qkv_b  = y_b    + 8388608;                 // region shared with h_b (64MB)
    short* h_b    = qkv_b;
    short* attn_b = qkv_b  + 33554432;
    short* q_b    = attn_b + 8388608;
    float* x1     = (float*)(q_b + 8388608);
    float* x2     = x1 + 8388608;
    short* kv_b   = (short*)(x2 + 8388608);

    const int ROWS  = BATCH * SEQ_T;   // 8192
    const int EROWS = BATCH * SEQ_I;   // 2056

    // weight transpose+cast (bf16 W^T)
    wcast_t<<<dim3(3072/32, 1024/32), 256, 0, stream>>>(w_qkv, wt_qkv, 1024, 3072);
    wcast_t<<<dim3(1024/32, 1024/32), 256, 0, stream>>>(w_ao,  wt_ao,  1024, 1024);
    wcast_t<<<dim3(1024/32, 1024/32), 256, 0, stream>>>(w_q,   wt_q,   1024, 1024);
    wcast_t<<<dim3(2048/32, 1024/32), 256, 0, stream>>>(w_kv,  wt_kv,  1024, 2048);
    wcast_t<<<dim3(1024/32, 1024/32), 256, 0, stream>>>(w_co,  wt_co,  1024, 1024);
    wcast_t<<<dim3(4096/32, 1024/32), 256, 0, stream>>>(w_fc,  wt_fc,  1024, 4096);
    wcast_t<<<dim3(1024/32, 4096/32), 256, 0, stream>>>(w_mo,  wt_mo,  4096, 1024);
    cast_bf16<<<2056, 256, 0, stream>>>(enc, enc_b);

    // 1. y1 = LN(x) -> bf16
    ln_bf16<<<ROWS, 256, 0, stream>>>(x, ln1_g, ln1_b, y_b);
    // 2. qkv = y1 @ w_qkv + b_qkv -> bf16 [8192,3072]
    gemm_mfma<0><<<dim3(3072/128, ROWS/128), 256, 0, stream>>>(
        y_b, wt_qkv, b_qkv, nullptr, qkv_b, ROWS, 3072, 1024, 1024);
    // 3. self attention (causal) -> bf16 [8192,1024]
    attn_scalar<true><<<512, 256, 0, stream>>>(
        qkv_b, qkv_b + 1024, qkv_b + 2048, attn_b, 3072, 3072, SEQ_T);
    // 4. x1 = x + attn @ w_ao + b_ao -> f32
    gemm_mfma<1><<<dim3(1024/128, ROWS/128), 256, 0, stream>>>(
        attn_b, wt_ao, b_ao, x, x1, ROWS, 1024, 1024, 1024);
    // 5. y2 = LN(x1) -> bf16
    ln_bf16<<<ROWS, 256, 0, stream>>>(x1, ln2_g, ln2_b, y_b);
    // 6. q = y2 @ w_q + b_q -> bf16
    gemm_mfma<0><<<dim3(1024/128, ROWS/128), 256, 0, stream>>>(
        y_b, wt_q, b_q, nullptr, q_b, ROWS, 1024, 1024, 1024);
    // 7. kv = enc @ w_kv + b_kv -> bf16 [2056,2048]
    gemm_mfma<0><<<dim3(2048/128, (EROWS+127)/128), 256, 0, stream>>>(
        enc_b, wt_kv, b_kv, nullptr, kv_b, EROWS, 2048, 1024, 1024);
    // 8. cross attention -> bf16 (reuse attn_b)
    attn_scalar<false><<<512, 256, 0, stream>>>(
        q_b, kv_b, kv_b + 1024, attn_b, 1024, 2048, SEQ_I);
    // 9. x2 = x1 + cross @ w_co + b_co -> f32
    gemm_mfma<1><<<dim3(1024/128, ROWS/128), 256, 0, stream>>>(
        attn_b, wt_co, b_co, x1, x2, ROWS, 1024, 1024, 1024);
    // 10. y3 = LN(x2) -> bf16
    ln_bf16<<<ROWS, 256, 0, stream>>>(x2, ln3_g, ln3_b, y_b);
    // 11. h = gelu(y3 @ w_fc + b_fc) -> bf16 [8192,4096]
    gemm_mfma<2><<<dim3(4096/128, ROWS/128), 256, 0, stream>>>(
        y_b, wt_fc, b_fc, nullptr, h_b, ROWS, 4096, 1024, 1024);
    // 12. out = x2 + h @ w_mo + b_mo -> f32
    gemm_mfma<1><<<dim3(1024/128, ROWS/128), 256, 0, stream>>>(
        h_b, wt_mo, b_mo, x2, outp, ROWS, 1024, 4096, 4096);
}

// Round 7
// 708.811 us; speedup vs baseline: 6.1742x; 2.9527x over previous
//
#include <hip/hip_runtime.h>
#include <hip/hip_bf16.h>

#define N_EMBD 1024
#define N_HEAD 16
#define HEAD_DIM 64
#define BATCH 8
#define SEQ_T 1024
#define SEQ_I 257

typedef __attribute__((ext_vector_type(8))) short short8_t;
typedef __attribute__((ext_vector_type(4))) float f32x4;

union U8 { uint4 u; short8_t s; };

// f32 -> bf16 RNE
static __device__ __forceinline__ unsigned short f2b(float f)
{
    unsigned int u = __float_as_uint(f);
    u = (u + 0x7fffu + ((u >> 16) & 1u)) >> 16;
    return (unsigned short)u;
}
static __device__ __forceinline__ float b2f_lo(unsigned int u) { return __uint_as_float(u << 16); }
static __device__ __forceinline__ float b2f_hi(unsigned int u) { return __uint_as_float(u & 0xffff0000u); }

__device__ __forceinline__ float gelu_tanh(float u)
{
    float z = 0.7978845608028654f * (u + 0.044715f * u * u * u);
    z = fmaxf(z, -15.0f);
    const float e = __expf(-2.0f * z);
    const float t = (1.0f - e) / (1.0f + e);
    return 0.5f * u * (1.0f + t);
}

// ---------------------------------------------------------------------------
// Weight transpose+cast: W[K,N] f32 -> WT[N,K] bf16
// ---------------------------------------------------------------------------
__global__ __launch_bounds__(256)
void wcast_t(const float* __restrict__ W, short* __restrict__ WT, int K, int N)
{
    __shared__ float t[32][33];
    const int n0 = blockIdx.x * 32, k0 = blockIdx.y * 32;
    const int c = threadIdx.x & 31, r4 = (threadIdx.x >> 5) * 4;
    #pragma unroll
    for (int i = 0; i < 4; ++i)
        t[r4 + i][c] = W[(size_t)(k0 + r4 + i) * N + n0 + c];
    __syncthreads();
    #pragma unroll
    for (int i = 0; i < 4; ++i)
        WT[(size_t)(n0 + r4 + i) * K + k0 + c] = (short)f2b(t[c][r4 + i]);
}

// elementwise f32 -> bf16 (enc), 4 elems/thread
__global__ __launch_bounds__(256)
void cast_bf16(const float* __restrict__ in, short* __restrict__ out)
{
    const int i = blockIdx.x * 256 + threadIdx.x;
    const float4 v = ((const float4*)in)[i];
    unsigned int w0 = (unsigned int)f2b(v.x) | ((unsigned int)f2b(v.y) << 16);
    unsigned int w1 = (unsigned int)f2b(v.z) | ((unsigned int)f2b(v.w) << 16);
    ((uint2*)out)[i] = make_uint2(w0, w1);
}

// ---------------------------------------------------------------------------
// LayerNorm: f32 in -> bf16 out. one block per row of 1024.
// ---------------------------------------------------------------------------
__global__ __launch_bounds__(256)
void ln_bf16(const float* __restrict__ in, const float* __restrict__ gamma,
             const float* __restrict__ beta, short* __restrict__ out)
{
    const int row = blockIdx.x;
    const int tid = threadIdx.x;
    const float4 v = *(const float4*)(in + (size_t)row * N_EMBD + tid * 4);
    float s  = v.x + v.y + v.z + v.w;
    float ss = v.x*v.x + v.y*v.y + v.z*v.z + v.w*v.w;
    #pragma unroll
    for (int off = 32; off >= 1; off >>= 1) {
        s  += __shfl_down(s,  off);
        ss += __shfl_down(ss, off);
    }
    __shared__ float rs[4], rss[4];
    const int wid = tid >> 6, lane = tid & 63;
    if (lane == 0) { rs[wid] = s; rss[wid] = ss; }
    __syncthreads();
    s  = rs[0] + rs[1] + rs[2] + rs[3];
    ss = rss[0] + rss[1] + rss[2] + rss[3];
    const float mean = s * (1.0f / N_EMBD);
    const float var  = ss * (1.0f / N_EMBD) - mean * mean;
    const float rstd = rsqrtf(var + 1e-5f);
    const float4 g = *(const float4*)(gamma + tid * 4);
    const float4 b = *(const float4*)(beta  + tid * 4);
    float o0 = (v.x - mean) * rstd * g.x + b.x;
    float o1 = (v.y - mean) * rstd * g.y + b.y;
    float o2 = (v.z - mean) * rstd * g.z + b.z;
    float o3 = (v.w - mean) * rstd * g.w + b.w;
    unsigned int w0 = (unsigned int)f2b(o0) | ((unsigned int)f2b(o1) << 16);
    unsigned int w1 = (unsigned int)f2b(o2) | ((unsigned int)f2b(o3) << 16);
    ((uint2*)(out + (size_t)row * N_EMBD))[tid] = make_uint2(w0, w1);
}

// ---------------------------------------------------------------------------
// bf16 MFMA GEMM: 128x128 tile, BK=32, 4 waves.
// ---------------------------------------------------------------------------
template<int EPI>
__global__ __launch_bounds__(256, 2)
void gemm_mfma(const short* __restrict__ A, const short* __restrict__ WT,
               const float* __restrict__ bias, const float* __restrict__ res,
               void* __restrict__ outv, int M, int N, int K, int lda)
{
    __shared__ short As[128 * 32];
    __shared__ short Bs[128 * 32];
    const int tid  = threadIdx.x;
    const int bm   = blockIdx.y * 128;
    const int bn   = blockIdx.x * 128;
    const int lane = tid & 63;
    const int wid  = tid >> 6;
    const int wr   = (wid >> 1) * 64;
    const int wc   = (wid & 1) * 64;
    const int fr   = lane & 15;
    const int kg   = lane >> 4;

    const int idx0 = tid;
    const int idx1 = 256 + tid;
    const int r0 = idx0 >> 2, g0 = (idx0 & 3) ^ ((r0 >> 1) & 3);
    const int r1 = idx1 >> 2, g1 = (idx1 & 3) ^ ((r1 >> 1) & 3);
    const short* aSrc0 = A  + (size_t)min(bm + r0, M - 1) * lda + g0 * 8;
    const short* aSrc1 = A  + (size_t)min(bm + r1, M - 1) * lda + g1 * 8;
    const short* bSrc0 = WT + (size_t)(bn + r0) * K + g0 * 8;
    const short* bSrc1 = WT + (size_t)(bn + r1) * K + g1 * 8;
    const int dst0 = (tid & ~63) * 16;
    const int dst1 = (256 + (tid & ~63)) * 16;

    int offA[4], offB[4];
    #pragma unroll
    for (int f = 0; f < 4; ++f) {
        const int ra = wr + f * 16 + fr;
        offA[f] = ra * 32 + ((kg ^ ((ra >> 1) & 3)) * 8);
        const int rb = wc + f * 16 + fr;
        offB[f] = rb * 32 + ((kg ^ ((rb >> 1) & 3)) * 8);
    }

    f32x4 acc[4][4];
    #pragma unroll
    for (int i = 0; i < 4; ++i)
        #pragma unroll
        for (int j = 0; j < 4; ++j)
            acc[i][j] = (f32x4){0.f, 0.f, 0.f, 0.f};

    for (int k0 = 0; k0 < K; k0 += 32) {
        __builtin_amdgcn_global_load_lds(
            (const __attribute__((address_space(1))) void*)(aSrc0 + k0),
            (__attribute__((address_space(3))) void*)((char*)As + dst0), 16, 0, 0);
        __builtin_amdgcn_global_load_lds(
            (const __attribute__((address_space(1))) void*)(aSrc1 + k0),
            (__attribute__((address_space(3))) void*)((char*)As + dst1), 16, 0, 0);
        __builtin_amdgcn_global_load_lds(
            (const __attribute__((address_space(1))) void*)(bSrc0 + k0),
            (__attribute__((address_space(3))) void*)((char*)Bs + dst0), 16, 0, 0);
        __builtin_amdgcn_global_load_lds(
            (const __attribute__((address_space(1))) void*)(bSrc1 + k0),
            (__attribute__((address_space(3))) void*)((char*)Bs + dst1), 16, 0, 0);
        __syncthreads();
        short8_t af[4], bf[4];
        #pragma unroll
        for (int f = 0; f < 4; ++f) {
            af[f] = *(const short8_t*)(As + offA[f]);
            bf[f] = *(const short8_t*)(Bs + offB[f]);
        }
        #pragma unroll
        for (int i = 0; i < 4; ++i)
            #pragma unroll
            for (int j = 0; j < 4; ++j)
                acc[i][j] = __builtin_amdgcn_mfma_f32_16x16x32_bf16(af[i], bf[j], acc[i][j], 0, 0, 0);
        __syncthreads();
    }

    #pragma unroll
    for (int i = 0; i < 4; ++i) {
        #pragma unroll
        for (int r = 0; r < 4; ++r) {
            const int m = bm + wr + i * 16 + kg * 4 + r;
            if (m >= M) continue;
            #pragma unroll
            for (int j = 0; j < 4; ++j) {
                const int n = bn + wc + j * 16 + fr;
                float v = acc[i][j][r] + bias[n];
                if (EPI == 1) v += res[(size_t)m * N + n];
                if (EPI == 2) v = gelu_tanh(v);
                if (EPI == 1) ((float*)outv)[(size_t)m * N + n] = v;
                else          ((short*)outv)[(size_t)m * N + n] = (short)f2b(v);
            }
        }
    }
}

// ---------------------------------------------------------------------------
// MFMA flash attention. Block = 64 q rows (4 waves x 16), KV tile = 32 keys.
// Swapped QK^T: S^T[key][q] = mfma(K_frag, Q_frag) -> per-lane softmax state
// for q = lane&15. P routed via per-wave LDS tile to A-frag layout; V staged
// transposed (pad 36). K staged linear via global_load_lds with XOR slot
// swizzle on the *source* (both-sides involution).
// ---------------------------------------------------------------------------
template<bool CAUSAL>
__global__ __launch_bounds__(256, 2)
void attn_mfma(const short* __restrict__ Qm, const short* __restrict__ Km,
               const short* __restrict__ Vm, short* __restrict__ out,
               int qStride, int kStride, int kRows)
{
    __shared__ short Ks[32 * 64];            // [key][64 d], slot-swizzled
    __shared__ unsigned int VtU[36 * 32];    // V^T [64 d][36 shorts] as uints
    __shared__ unsigned int PA[4][320];      // per wave: P[16 q][40 shorts]

    const int tid  = threadIdx.x;
    const int lane = tid & 63;
    const int wid  = tid >> 6;
    const int bid  = blockIdx.x;
    const int qt   = CAUSAL ? (15 - (bid >> 7)) : (bid >> 7);
    const int bh   = bid & 127;
    const int b    = bh >> 4, h = bh & 15;
    const int qb   = qt * 64;
    const int fr   = lane & 15;
    const int g    = lane >> 4;

    // Q frags (2nd MFMA operand): row q = qb + wid*16 + fr
    const int qrow = qb + wid * 16 + fr;
    const short* qptr = Qm + (size_t)(b * SEQ_T + qrow) * qStride + h * HEAD_DIM + g * 8;
    U8 qf0, qf1;
    qf0.u = *(const uint4*)(qptr);
    qf1.u = *(const uint4*)(qptr + 32);

    f32x4 accO[4];
    #pragma unroll
    for (int i = 0; i < 4; ++i) accO[i] = (f32x4){0.f, 0.f, 0.f, 0.f};
    float mrun = -1e30f, lrun = 0.f;

    const int ntiles = CAUSAL ? (2 * qt + 2) : ((kRows + 31) >> 5);
    const size_t kbase = (size_t)b * kRows;

    for (int it = 0; it < ntiles; ++it) {
        const int kb = it * 32;
        __syncthreads();   // prior iteration's LDS reads done (full drain)

        // --- stage K (linear dest, source-swizzled slot) ---
        {
            const int krow  = min(kb + (tid >> 3), kRows - 1);
            const int gslot = (tid & 7) ^ ((tid >> 3) & 7);
            __builtin_amdgcn_global_load_lds(
                (const __attribute__((address_space(1))) void*)
                    (Km + (kbase + krow) * (size_t)kStride + h * HEAD_DIM + gslot * 8),
                (__attribute__((address_space(3))) void*)((char*)Ks + tid * 16), 16, 0, 0);
        }
        // --- stage V transposed: Vt[d][key], pad 36 ---
        #pragma unroll
        for (int v = 0; v < 2; ++v) {
            const int idx = v * 256 + tid;
            const int d2 = idx & 31, kp = idx >> 5;
            const int kr0 = min(kb + 2 * kp,     kRows - 1);
            const int kr1 = min(kb + 2 * kp + 1, kRows - 1);
            const unsigned int u0 = *(const unsigned int*)
                (Vm + (kbase + kr0) * (size_t)kStride + h * HEAD_DIM + 2 * d2);
            const unsigned int u1 = *(const unsigned int*)
                (Vm + (kbase + kr1) * (size_t)kStride + h * HEAD_DIM + 2 * d2);
            VtU[36 * d2 + kp]      = (u0 & 0xffffu) | (u1 << 16);
            VtU[36 * d2 + 18 + kp] = (u0 >> 16)    | (u1 & 0xffff0000u);
        }
        __syncthreads();

        // --- QK^T (swapped): s0 = keys kb..kb+15, s1 = keys kb+16..kb+31 ---
        f32x4 s0 = (f32x4){0.f,0.f,0.f,0.f}, s1 = (f32x4){0.f,0.f,0.f,0.f};
        {
            const uint4* K4 = (const uint4*)Ks;
            U8 ka;
            ka.u = K4[8 * fr        + ((g)     ^ (fr & 7))];
            s0 = __builtin_amdgcn_mfma_f32_16x16x32_bf16(ka.s, qf0.s, s0, 0, 0, 0);
            ka.u = K4[8 * fr        + ((4 + g) ^ (fr & 7))];
            s0 = __builtin_amdgcn_mfma_f32_16x16x32_bf16(ka.s, qf1.s, s0, 0, 0, 0);
            ka.u = K4[8 * (16 + fr) + ((g)     ^ (fr & 7))];
            s1 = __builtin_amdgcn_mfma_f32_16x16x32_bf16(ka.s, qf0.s, s1, 0, 0, 0);
            ka.u = K4[8 * (16 + fr) + ((4 + g) ^ (fr & 7))];
            s1 = __builtin_amdgcn_mfma_f32_16x16x32_bf16(ka.s, qf1.s, s1, 0, 0, 0);
        }

        // --- masked online softmax (state per lane for q = fr) ---
        float sv[8];
        #pragma unroll
        for (int r = 0; r < 4; ++r) {
            sv[r]     = s0[r] * 0.125f;
            sv[4 + r] = s1[r] * 0.125f;
            const int k0 = kb + 4 * g + r;
            const int k1 = k0 + 16;
            if (CAUSAL ? (k0 > qrow) : (k0 >= kRows)) sv[r]     = -1e30f;
            if (CAUSAL ? (k1 > qrow) : (k1 >= kRows)) sv[4 + r] = -1e30f;
        }
        float tm = sv[0];
        #pragma unroll
        for (int j = 1; j < 8; ++j) tm = fmaxf(tm, sv[j]);
        tm = fmaxf(tm, __shfl_xor(tm, 16));
        tm = fmaxf(tm, __shfl_xor(tm, 32));
        const float newm = fmaxf(mrun, tm);
        const float fs = __expf(mrun - newm);
        mrun = newm;
        float p[8], ps = 0.f;
        #pragma unroll
        for (int j = 0; j < 8; ++j) { p[j] = __expf(sv[j] - newm); ps += p[j]; }
        ps += __shfl_xor(ps, 16);
        ps += __shfl_xor(ps, 32);
        lrun = lrun * fs + ps;

        // rescale O (O rows live at q = 4*g + r)
        float frr[4];
        #pragma unroll
        for (int r = 0; r < 4; ++r) frr[r] = __shfl(fs, 4 * g + r);
        #pragma unroll
        for (int db = 0; db < 4; ++db)
            #pragma unroll
            for (int r = 0; r < 4; ++r) accO[db][r] *= frr[r];

        // --- P -> LDS (bf16, A-frag layout) ---
        {
            uint2* paw = (uint2*)PA[wid];
            paw[10 * fr + g] = make_uint2(
                (unsigned int)f2b(p[0]) | ((unsigned int)f2b(p[1]) << 16),
                (unsigned int)f2b(p[2]) | ((unsigned int)f2b(p[3]) << 16));
            paw[10 * fr + 4 + g] = make_uint2(
                (unsigned int)f2b(p[4]) | ((unsigned int)f2b(p[5]) << 16),
                (unsigned int)f2b(p[6]) | ((unsigned int)f2b(p[7]) << 16));
        }
        U8 pf;
        pf.u = ((const uint4*)PA[wid])[5 * fr + g];

        // --- PV: accO[db] += P[q][k] * V^T[d][k] ---
        #pragma unroll
        for (int db = 0; db < 4; ++db) {
            const int d = db * 16 + fr;
            const uint2 v0 = ((const uint2*)VtU)[9 * d + 2 * g];
            const uint2 v1 = ((const uint2*)VtU)[9 * d + 2 * g + 1];
            U8 vf; vf.u = make_uint4(v0.x, v0.y, v1.x, v1.y);
            accO[db] = __builtin_amdgcn_mfma_f32_16x16x32_bf16(pf.s, vf.s, accO[db], 0, 0, 0);
        }
    }

    // --- epilogue: normalize and store (O rows at q = 4*g + r) ---
    float lr[4];
    #pragma unroll
    for (int r = 0; r < 4; ++r) lr[r] = 1.0f / __shfl(lrun, 4 * g + r);
    #pragma unroll
    for (int db = 0; db < 4; ++db) {
        #pragma unroll
        for (int r = 0; r < 4; ++r) {
            const int row = qb + wid * 16 + 4 * g + r;
            const int col = h * HEAD_DIM + db * 16 + fr;
            out[(size_t)(b * SEQ_T + row) * N_EMBD + col] = (short)f2b(accO[db][r] * lr[r]);
        }
    }
}

// ---------------------------------------------------------------------------
// launch
// ---------------------------------------------------------------------------
extern "C" void kernel_launch(void* const* d_in, const int* in_sizes, int n_in,
                              void* d_out, int out_size, void* d_ws, size_t ws_size,
                              hipStream_t stream)
{
    const float* x     = (const float*)d_in[0];
    const float* enc   = (const float*)d_in[1];
    const float* ln1_g = (const float*)d_in[2];
    const float* ln1_b = (const float*)d_in[3];
    const float* ln2_g = (const float*)d_in[4];
    const float* ln2_b = (const float*)d_in[5];
    const float* ln3_g = (const float*)d_in[6];
    const float* ln3_b = (const float*)d_in[7];
    const float* w_qkv = (const float*)d_in[8];
    const float* b_qkv = (const float*)d_in[9];
    const float* w_ao  = (const float*)d_in[10];
    const float* b_ao  = (const float*)d_in[11];
    const float* w_q   = (const float*)d_in[12];
    const float* b_q   = (const float*)d_in[13];
    const float* w_kv  = (const float*)d_in[14];
    const float* b_kv  = (const float*)d_in[15];
    const float* w_co  = (const float*)d_in[16];
    const float* b_co  = (const float*)d_in[17];
    const float* w_fc  = (const float*)d_in[18];
    const float* b_fc  = (const float*)d_in[19];
    const float* w_mo  = (const float*)d_in[20];
    const float* b_mo  = (const float*)d_in[21];
    float* outp = (float*)d_out;

    // workspace layout
    short* wt_qkv = (short*)d_ws;
    short* wt_ao  = wt_qkv + 3145728;
    short* wt_q   = wt_ao  + 1048576;
    short* wt_kv  = wt_q   + 1048576;
    short* wt_co  = wt_kv  + 2097152;
    short* wt_fc  = wt_co  + 1048576;
    short* wt_mo  = wt_fc  + 4194304;
    short* enc_b  = wt_mo  + 4194304;                 // 2,105,344 bf16
    short* y_b    = enc_b  + 2105344;                 // 8,388,608 bf16
    short* qkv_b  = y_b    + 8388608;                 // region shared with h_b
    short* h_b    = qkv_b;
    short* attn_b = qkv_b  + 33554432;
    short* q_b    = attn_b + 8388608;
    float* x1     = (float*)(q_b + 8388608);
    float* x2     = x1 + 8388608;
    short* kv_b   = (short*)(x2 + 8388608);

    const int ROWS  = BATCH * SEQ_T;   // 8192
    const int EROWS = BATCH * SEQ_I;   // 2056

    // weight transpose+cast (bf16 W^T)
    wcast_t<<<dim3(3072/32, 1024/32), 256, 0, stream>>>(w_qkv, wt_qkv, 1024, 3072);
    wcast_t<<<dim3(1024/32, 1024/32), 256, 0, stream>>>(w_ao,  wt_ao,  1024, 1024);
    wcast_t<<<dim3(1024/32, 1024/32), 256, 0, stream>>>(w_q,   wt_q,   1024, 1024);
    wcast_t<<<dim3(2048/32, 1024/32), 256, 0, stream>>>(w_kv,  wt_kv,  1024, 2048);
    wcast_t<<<dim3(1024/32, 1024/32), 256, 0, stream>>>(w_co,  wt_co,  1024, 1024);
    wcast_t<<<dim3(4096/32, 1024/32), 256, 0, stream>>>(w_fc,  wt_fc,  1024, 4096);
    wcast_t<<<dim3(1024/32, 4096/32), 256, 0, stream>>>(w_mo,  wt_mo,  4096, 1024);
    cast_bf16<<<2056, 256, 0, stream>>>(enc, enc_b);

    // 1. y1 = LN(x) -> bf16
    ln_bf16<<<ROWS, 256, 0, stream>>>(x, ln1_g, ln1_b, y_b);
    // 2. qkv = y1 @ w_qkv + b_qkv -> bf16 [8192,3072]
    gemm_mfma<0><<<dim3(3072/128, ROWS/128), 256, 0, stream>>>(
        y_b, wt_qkv, b_qkv, nullptr, qkv_b, ROWS, 3072, 1024, 1024);
    // 3. self attention (causal, MFMA) -> bf16 [8192,1024]
    attn_mfma<true><<<2048, 256, 0, stream>>>(
        qkv_b, qkv_b + 1024, qkv_b + 2048, attn_b, 3072, 3072, SEQ_T);
    // 4. x1 = x + attn @ w_ao + b_ao -> f32
    gemm_mfma<1><<<dim3(1024/128, ROWS/128), 256, 0, stream>>>(
        attn_b, wt_ao, b_ao, x, x1, ROWS, 1024, 1024, 1024);
    // 5. y2 = LN(x1) -> bf16
    ln_bf16<<<ROWS, 256, 0, stream>>>(x1, ln2_g, ln2_b, y_b);
    // 6. q = y2 @ w_q + b_q -> bf16
    gemm_mfma<0><<<dim3(1024/128, ROWS/128), 256, 0, stream>>>(
        y_b, wt_q, b_q, nullptr, q_b, ROWS, 1024, 1024, 1024);
    // 7. kv = enc @ w_kv + b_kv -> bf16 [2056,2048]
    gemm_mfma<0><<<dim3(2048/128, (EROWS+127)/128), 256, 0, stream>>>(
        enc_b, wt_kv, b_kv, nullptr, kv_b, EROWS, 2048, 1024, 1024);
    // 8. cross attention (MFMA) -> bf16 (reuse attn_b)
    attn_mfma<false><<<2048, 256, 0, stream>>>(
        q_b, kv_b, kv_b + 1024, attn_b, 1024, 2048, SEQ_I);
    // 9. x2 = x1 + cross @ w_co + b_co -> f32
    gemm_mfma<1><<<dim3(1024/128, ROWS/128), 256, 0, stream>>>(
        attn_b, wt_co, b_co, x1, x2, ROWS, 1024, 1024, 1024);
    // 10. y3 = LN(x2) -> bf16
    ln_bf16<<<ROWS, 256, 0, stream>>>(x2, ln3_g, ln3_b, y_b);
    // 11. h = gelu(y3 @ w_fc + b_fc) -> bf16 [8192,4096]
    gemm_mfma<2><<<dim3(4096/128, ROWS/128), 256, 0, stream>>>(
        y_b, wt_fc, b_fc, nullptr, h_b, ROWS, 4096, 1024, 1024);
    // 12. out = x2 + h @ w_mo + b_mo -> f32
    gemm_mfma<1><<<dim3(1024/128, ROWS/128), 256, 0, stream>>>(
        h_b, wt_mo, b_mo, x2, outp, ROWS, 1024, 4096, 4096);
}

// Round 9
// 672.101 us; speedup vs baseline: 6.5115x; 1.0546x over previous
//
#include <hip/hip_runtime.h>
#include <hip/hip_bf16.h>

#define N_EMBD 1024
#define N_HEAD 16
#define HEAD_DIM 64
#define BATCH 8
#define SEQ_T 1024
#define SEQ_I 257

typedef __attribute__((ext_vector_type(8))) short short8_t;
typedef __attribute__((ext_vector_type(4))) float f32x4;

union U8 { uint4 u; short8_t s; };

// f32 -> bf16 RNE
static __device__ __forceinline__ unsigned short f2b(float f)
{
    unsigned int u = __float_as_uint(f);
    u = (u + 0x7fffu + ((u >> 16) & 1u)) >> 16;
    return (unsigned short)u;
}

__device__ __forceinline__ float gelu_tanh(float u)
{
    float z = 0.7978845608028654f * (u + 0.044715f * u * u * u);
    z = fmaxf(z, -15.0f);
    const float e = __expf(-2.0f * z);
    const float t = (1.0f - e) / (1.0f + e);
    return 0.5f * u * (1.0f + t);
}

// ---------------------------------------------------------------------------
// Weight transpose+cast: W[K,N] f32 -> WT[N,K] bf16
// ---------------------------------------------------------------------------
__global__ __launch_bounds__(256)
void wcast_t(const float* __restrict__ W, short* __restrict__ WT, int K, int N)
{
    __shared__ float t[32][33];
    const int n0 = blockIdx.x * 32, k0 = blockIdx.y * 32;
    const int c = threadIdx.x & 31, r4 = (threadIdx.x >> 5) * 4;
    #pragma unroll
    for (int i = 0; i < 4; ++i)
        t[r4 + i][c] = W[(size_t)(k0 + r4 + i) * N + n0 + c];
    __syncthreads();
    #pragma unroll
    for (int i = 0; i < 4; ++i)
        WT[(size_t)(n0 + r4 + i) * K + k0 + c] = (short)f2b(t[c][r4 + i]);
}

// elementwise f32 -> bf16 (enc), 4 elems/thread
__global__ __launch_bounds__(256)
void cast_bf16(const float* __restrict__ in, short* __restrict__ out)
{
    const int i = blockIdx.x * 256 + threadIdx.x;
    const float4 v = ((const float4*)in)[i];
    unsigned int w0 = (unsigned int)f2b(v.x) | ((unsigned int)f2b(v.y) << 16);
    unsigned int w1 = (unsigned int)f2b(v.z) | ((unsigned int)f2b(v.w) << 16);
    ((uint2*)out)[i] = make_uint2(w0, w1);
}

// ---------------------------------------------------------------------------
// LayerNorm: f32 in -> bf16 out. one block per row of 1024.
// ---------------------------------------------------------------------------
__global__ __launch_bounds__(256)
void ln_bf16(const float* __restrict__ in, const float* __restrict__ gamma,
             const float* __restrict__ beta, short* __restrict__ out)
{
    const int row = blockIdx.x;
    const int tid = threadIdx.x;
    const float4 v = *(const float4*)(in + (size_t)row * N_EMBD + tid * 4);
    float s  = v.x + v.y + v.z + v.w;
    float ss = v.x*v.x + v.y*v.y + v.z*v.z + v.w*v.w;
    #pragma unroll
    for (int off = 32; off >= 1; off >>= 1) {
        s  += __shfl_down(s,  off);
        ss += __shfl_down(ss, off);
    }
    __shared__ float rs[4], rss[4];
    const int wid = tid >> 6, lane = tid & 63;
    if (lane == 0) { rs[wid] = s; rss[wid] = ss; }
    __syncthreads();
    s  = rs[0] + rs[1] + rs[2] + rs[3];
    ss = rss[0] + rss[1] + rss[2] + rss[3];
    const float mean = s * (1.0f / N_EMBD);
    const float var  = ss * (1.0f / N_EMBD) - mean * mean;
    const float rstd = rsqrtf(var + 1e-5f);
    const float4 g = *(const float4*)(gamma + tid * 4);
    const float4 b = *(const float4*)(beta  + tid * 4);
    float o0 = (v.x - mean) * rstd * g.x + b.x;
    float o1 = (v.y - mean) * rstd * g.y + b.y;
    float o2 = (v.z - mean) * rstd * g.z + b.z;
    float o3 = (v.w - mean) * rstd * g.w + b.w;
    unsigned int w0 = (unsigned int)f2b(o0) | ((unsigned int)f2b(o1) << 16);
    unsigned int w1 = (unsigned int)f2b(o2) | ((unsigned int)f2b(o3) << 16);
    ((uint2*)(out + (size_t)row * N_EMBD))[tid] = make_uint2(w0, w1);
}

// ---------------------------------------------------------------------------
// bf16 MFMA GEMM v2: 128x128 tile, BK=64, double-buffered LDS, 2-phase
// prefetch (issue next-tile global_load_lds BEFORE computing current tile),
// XCD-chunked block swizzle (1D grid, gridDim.x % 8 == 0).
// LDS involution: slot s of row r holds global k-group s ^ (r&7).
// EPI: 0 = bias -> bf16 out; 1 = bias + res(f32) -> f32 out; 2 = bias+gelu -> bf16
// ---------------------------------------------------------------------------
template<int EPI>
__global__ __launch_bounds__(256, 2)
void gemm_mfma(const short* __restrict__ A, const short* __restrict__ WT,
               const float* __restrict__ bias, const float* __restrict__ res,
               void* __restrict__ outv, int M, int N, int K, int lda, int gnx)
{
    __shared__ short As[2][128 * 64];
    __shared__ short Bs[2][128 * 64];
    const int tid  = threadIdx.x;

    // XCD-chunked bijective swizzle: each XCD gets a contiguous lin range
    // (disjoint m-rows -> A panels fetched once per chip, reused via L2).
    const int nwg = gridDim.x;
    const int lin = (blockIdx.x & 7) * (nwg >> 3) + (blockIdx.x >> 3);
    const int bm  = (lin / gnx) * 128;
    const int bn  = (lin % gnx) * 128;

    const int lane = tid & 63;
    const int wid  = tid >> 6;
    const int wr   = (wid >> 1) * 64;
    const int wc   = (wid & 1) * 64;
    const int fr   = lane & 15;
    const int kg   = lane >> 4;

    // staging constants: thread covers idx = p*256+tid, row = p*32 + (tid>>3),
    // LDS slot = tid&7, global k-group = (tid&7) ^ (row&7)  [p*32 % 8 == 0]
    const int r_ = tid >> 3;
    const int g_ = (tid & 7) ^ (r_ & 7);
    const int dstbase = (tid & ~63) * 16;

    #define STAGE(buf, k0)                                                          \
        _Pragma("unroll")                                                           \
        for (int p = 0; p < 4; ++p) {                                               \
            const int rowA = min(bm + p * 32 + r_, M - 1);                          \
            __builtin_amdgcn_global_load_lds(                                       \
                (const __attribute__((address_space(1))) void*)                     \
                    (A + (size_t)rowA * lda + (k0) + g_ * 8),                       \
                (__attribute__((address_space(3))) void*)                           \
                    ((char*)As[buf] + p * 4096 + dstbase), 16, 0, 0);               \
            const int rowB = bn + p * 32 + r_;                                      \
            __builtin_amdgcn_global_load_lds(                                       \
                (const __attribute__((address_space(1))) void*)                     \
                    (WT + (size_t)rowB * K + (k0) + g_ * 8),                        \
                (__attribute__((address_space(3))) void*)                           \
                    ((char*)Bs[buf] + p * 4096 + dstbase), 16, 0, 0);               \
        }

    f32x4 acc[4][4];
    #pragma unroll
    for (int i = 0; i < 4; ++i)
        #pragma unroll
        for (int j = 0; j < 4; ++j)
            acc[i][j] = (f32x4){0.f, 0.f, 0.f, 0.f};

    // prologue
    STAGE(0, 0);
    __syncthreads();

    const int nkt = K >> 6;
    for (int kt = 0; kt < nkt; ++kt) {
        const int cur = kt & 1;
        if (kt + 1 < nkt) { STAGE(cur ^ 1, (kt + 1) << 6); }

        const short* AsC = As[cur];
        const short* BsC = Bs[cur];
        #pragma unroll
        for (int kk = 0; kk < 2; ++kk) {
            short8_t af[4], bf[4];
            #pragma unroll
            for (int f = 0; f < 4; ++f) {
                const int ra = wr + f * 16 + fr;
                af[f] = *(const short8_t*)(AsC + ra * 64 + (((kk * 4 + kg) ^ (ra & 7)) * 8));
                const int rb = wc + f * 16 + fr;
                bf[f] = *(const short8_t*)(BsC + rb * 64 + (((kk * 4 + kg) ^ (rb & 7)) * 8));
            }
            #pragma unroll
            for (int i = 0; i < 4; ++i)
                #pragma unroll
                for (int j = 0; j < 4; ++j)
                    acc[i][j] = __builtin_amdgcn_mfma_f32_16x16x32_bf16(af[i], bf[j], acc[i][j], 0, 0, 0);
        }
        // drains vmcnt(0) (prefetch landed) + protects buf reuse
        __syncthreads();
    }
    #undef STAGE

    // epilogue: C/D frag: n = lane&15, m = (lane>>4)*4 + r
    #pragma unroll
    for (int i = 0; i < 4; ++i) {
        #pragma unroll
        for (int r = 0; r < 4; ++r) {
            const int m = bm + wr + i * 16 + kg * 4 + r;
            if (m >= M) continue;
            #pragma unroll
            for (int j = 0; j < 4; ++j) {
                const int n = bn + wc + j * 16 + fr;
                float v = acc[i][j][r] + bias[n];
                if (EPI == 1) v += res[(size_t)m * N + n];
                if (EPI == 2) v = gelu_tanh(v);
                if (EPI == 1) ((float*)outv)[(size_t)m * N + n] = v;
                else          ((short*)outv)[(size_t)m * N + n] = (short)f2b(v);
            }
        }
    }
}

// ---------------------------------------------------------------------------
// MFMA flash attention (unchanged from round 7).
// ---------------------------------------------------------------------------
template<bool CAUSAL>
__global__ __launch_bounds__(256, 2)
void attn_mfma(const short* __restrict__ Qm, const short* __restrict__ Km,
               const short* __restrict__ Vm, short* __restrict__ out,
               int qStride, int kStride, int kRows)
{
    __shared__ short Ks[32 * 64];            // [key][64 d], slot-swizzled
    __shared__ unsigned int VtU[36 * 32];    // V^T [64 d][36 shorts] as uints
    __shared__ unsigned int PA[4][320];      // per wave: P[16 q][40 shorts]

    const int tid  = threadIdx.x;
    const int lane = tid & 63;
    const int wid  = tid >> 6;
    const int bid  = blockIdx.x;
    const int qt   = CAUSAL ? (15 - (bid >> 7)) : (bid >> 7);
    const int bh   = bid & 127;
    const int b    = bh >> 4, h = bh & 15;
    const int qb   = qt * 64;
    const int fr   = lane & 15;
    const int g    = lane >> 4;

    const int qrow = qb + wid * 16 + fr;
    const short* qptr = Qm + (size_t)(b * SEQ_T + qrow) * qStride + h * HEAD_DIM + g * 8;
    U8 qf0, qf1;
    qf0.u = *(const uint4*)(qptr);
    qf1.u = *(const uint4*)(qptr + 32);

    f32x4 accO[4];
    #pragma unroll
    for (int i = 0; i < 4; ++i) accO[i] = (f32x4){0.f, 0.f, 0.f, 0.f};
    float mrun = -1e30f, lrun = 0.f;

    const int ntiles = CAUSAL ? (2 * qt + 2) : ((kRows + 31) >> 5);
    const size_t kbase = (size_t)b * kRows;

    for (int it = 0; it < ntiles; ++it) {
        const int kb = it * 32;
        __syncthreads();

        {
            const int krow  = min(kb + (tid >> 3), kRows - 1);
            const int gslot = (tid & 7) ^ ((tid >> 3) & 7);
            __builtin_amdgcn_global_load_lds(
                (const __attribute__((address_space(1))) void*)
                    (Km + (kbase + krow) * (size_t)kStride + h * HEAD_DIM + gslot * 8),
                (__attribute__((address_space(3))) void*)((char*)Ks + tid * 16), 16, 0, 0);
        }
        #pragma unroll
        for (int v = 0; v < 2; ++v) {
            const int idx = v * 256 + tid;
            const int d2 = idx & 31, kp = idx >> 5;
            const int kr0 = min(kb + 2 * kp,     kRows - 1);
            const int kr1 = min(kb + 2 * kp + 1, kRows - 1);
            const unsigned int u0 = *(const unsigned int*)
                (Vm + (kbase + kr0) * (size_t)kStride + h * HEAD_DIM + 2 * d2);
            const unsigned int u1 = *(const unsigned int*)
                (Vm + (kbase + kr1) * (size_t)kStride + h * HEAD_DIM + 2 * d2);
            VtU[36 * d2 + kp]      = (u0 & 0xffffu) | (u1 << 16);
            VtU[36 * d2 + 18 + kp] = (u0 >> 16)    | (u1 & 0xffff0000u);
        }
        __syncthreads();

        f32x4 s0 = (f32x4){0.f,0.f,0.f,0.f}, s1 = (f32x4){0.f,0.f,0.f,0.f};
        {
            const uint4* K4 = (const uint4*)Ks;
            U8 ka;
            ka.u = K4[8 * fr        + ((g)     ^ (fr & 7))];
            s0 = __builtin_amdgcn_mfma_f32_16x16x32_bf16(ka.s, qf0.s, s0, 0, 0, 0);
            ka.u = K4[8 * fr        + ((4 + g) ^ (fr & 7))];
            s0 = __builtin_amdgcn_mfma_f32_16x16x32_bf16(ka.s, qf1.s, s0, 0, 0, 0);
            ka.u = K4[8 * (16 + fr) + ((g)     ^ (fr & 7))];
            s1 = __builtin_amdgcn_mfma_f32_16x16x32_bf16(ka.s, qf0.s, s1, 0, 0, 0);
            ka.u = K4[8 * (16 + fr) + ((4 + g) ^ (fr & 7))];
            s1 = __builtin_amdgcn_mfma_f32_16x16x32_bf16(ka.s, qf1.s, s1, 0, 0, 0);
        }

        float sv[8];
        #pragma unroll
        for (int r = 0; r < 4; ++r) {
            sv[r]     = s0[r] * 0.125f;
            sv[4 + r] = s1[r] * 0.125f;
            const int k0 = kb + 4 * g + r;
            const int k1 = k0 + 16;
            if (CAUSAL ? (k0 > qrow) : (k0 >= kRows)) sv[r]     = -1e30f;
            if (CAUSAL ? (k1 > qrow) : (k1 >= kRows)) sv[4 + r] = -1e30f;
        }
        float tm = sv[0];
        #pragma unroll
        for (int j = 1; j < 8; ++j) tm = fmaxf(tm, sv[j]);
        tm = fmaxf(tm, __shfl_xor(tm, 16));
        tm = fmaxf(tm, __shfl_xor(tm, 32));
        const float newm = fmaxf(mrun, tm);
        const float fs = __expf(mrun - newm);
        mrun = newm;
        float p[8], ps = 0.f;
        #pragma unroll
        for (int j = 0; j < 8; ++j) { p[j] = __expf(sv[j] - newm); ps += p[j]; }
        ps += __shfl_xor(ps, 16);
        ps += __shfl_xor(ps, 32);
        lrun = lrun * fs + ps;

        float frr[4];
        #pragma unroll
        for (int r = 0; r < 4; ++r) frr[r] = __shfl(fs, 4 * g + r);
        #pragma unroll
        for (int db = 0; db < 4; ++db)
            #pragma unroll
            for (int r = 0; r < 4; ++r) accO[db][r] *= frr[r];

        {
            uint2* paw = (uint2*)PA[wid];
            paw[10 * fr + g] = make_uint2(
                (unsigned int)f2b(p[0]) | ((unsigned int)f2b(p[1]) << 16),
                (unsigned int)f2b(p[2]) | ((unsigned int)f2b(p[3]) << 16));
            paw[10 * fr + 4 + g] = make_uint2(
                (unsigned int)f2b(p[4]) | ((unsigned int)f2b(p[5]) << 16),
                (unsigned int)f2b(p[6]) | ((unsigned int)f2b(p[7]) << 16));
        }
        U8 pf;
        pf.u = ((const uint4*)PA[wid])[5 * fr + g];

        #pragma unroll
        for (int db = 0; db < 4; ++db) {
            const int d = db * 16 + fr;
            const uint2 v0 = ((const uint2*)VtU)[9 * d + 2 * g];
            const uint2 v1 = ((const uint2*)VtU)[9 * d + 2 * g + 1];
            U8 vf; vf.u = make_uint4(v0.x, v0.y, v1.x, v1.y);
            accO[db] = __builtin_amdgcn_mfma_f32_16x16x32_bf16(pf.s, vf.s, accO[db], 0, 0, 0);
        }
    }

    float lr[4];
    #pragma unroll
    for (int r = 0; r < 4; ++r) lr[r] = 1.0f / __shfl(lrun, 4 * g + r);
    #pragma unroll
    for (int db = 0; db < 4; ++db) {
        #pragma unroll
        for (int r = 0; r < 4; ++r) {
            const int row = qb + wid * 16 + 4 * g + r;
            const int col = h * HEAD_DIM + db * 16 + fr;
            out[(size_t)(b * SEQ_T + row) * N_EMBD + col] = (short)f2b(accO[db][r] * lr[r]);
        }
    }
}

// ---------------------------------------------------------------------------
// launch
// ---------------------------------------------------------------------------
extern "C" void kernel_launch(void* const* d_in, const int* in_sizes, int n_in,
                              void* d_out, int out_size, void* d_ws, size_t ws_size,
                              hipStream_t stream)
{
    const float* x     = (const float*)d_in[0];
    const float* enc   = (const float*)d_in[1];
    const float* ln1_g = (const float*)d_in[2];
    const float* ln1_b = (const float*)d_in[3];
    const float* ln2_g = (const float*)d_in[4];
    const float* ln2_b = (const float*)d_in[5];
    const float* ln3_g = (const float*)d_in[6];
    const float* ln3_b = (const float*)d_in[7];
    const float* w_qkv = (const float*)d_in[8];
    const float* b_qkv = (const float*)d_in[9];
    const float* w_ao  = (const float*)d_in[10];
    const float* b_ao  = (const float*)d_in[11];
    const float* w_q   = (const float*)d_in[12];
    const float* b_q   = (const float*)d_in[13];
    const float* w_kv  = (const float*)d_in[14];
    const float* b_kv  = (const float*)d_in[15];
    const float* w_co  = (const float*)d_in[16];
    const float* b_co  = (const float*)d_in[17];
    const float* w_fc  = (const float*)d_in[18];
    const float* b_fc  = (const float*)d_in[19];
    const float* w_mo  = (const float*)d_in[20];
    const float* b_mo  = (const float*)d_in[21];
    float* outp = (float*)d_out;

    // workspace layout
    short* wt_qkv = (short*)d_ws;
    short* wt_ao  = wt_qkv + 3145728;
    short* wt_q   = wt_ao  + 1048576;
    short* wt_kv  = wt_q   + 1048576;
    short* wt_co  = wt_kv  + 2097152;
    short* wt_fc  = wt_co  + 1048576;
    short* wt_mo  = wt_fc  + 4194304;
    short* enc_b  = wt_mo  + 4194304;                 // 2,105,344 bf16
    short* y_b    = enc_b  + 2105344;                 // 8,388,608 bf16
    short* qkv_b  = y_b    + 8388608;                 // region shared with h_b
    short* h_b    = qkv_b;
    short* attn_b = qkv_b  + 33554432;
    short* q_b    = attn_b + 8388608;
    float* x1     = (float*)(q_b + 8388608);
    float* x2     = x1 + 8388608;
    short* kv_b   = (short*)(x2 + 8388608);

    const int ROWS  = BATCH * SEQ_T;   // 8192
    const int EROWS = BATCH * SEQ_I;   // 2056

    // weight transpose+cast (bf16 W^T)
    wcast_t<<<dim3(3072/32, 1024/32), 256, 0, stream>>>(w_qkv, wt_qkv, 1024, 3072);
    wcast_t<<<dim3(1024/32, 1024/32), 256, 0, stream>>>(w_ao,  wt_ao,  1024, 1024);
    wcast_t<<<dim3(1024/32, 1024/32), 256, 0, stream>>>(w_q,   wt_q,   1024, 1024);
    wcast_t<<<dim3(2048/32, 1024/32), 256, 0, stream>>>(w_kv,  wt_kv,  1024, 2048);
    wcast_t<<<dim3(1024/32, 1024/32), 256, 0, stream>>>(w_co,  wt_co,  1024, 1024);
    wcast_t<<<dim3(4096/32, 1024/32), 256, 0, stream>>>(w_fc,  wt_fc,  1024, 4096);
    wcast_t<<<dim3(1024/32, 4096/32), 256, 0, stream>>>(w_mo,  wt_mo,  4096, 1024);
    cast_bf16<<<2056, 256, 0, stream>>>(enc, enc_b);

    // 1. y1 = LN(x) -> bf16
    ln_bf16<<<ROWS, 256, 0, stream>>>(x, ln1_g, ln1_b, y_b);
    // 2. qkv = y1 @ w_qkv + b_qkv -> bf16 [8192,3072]   grid 24*64=1536
    gemm_mfma<0><<<1536, 256, 0, stream>>>(
        y_b, wt_qkv, b_qkv, nullptr, qkv_b, ROWS, 3072, 1024, 1024, 24);
    // 3. self attention (causal, MFMA) -> bf16 [8192,1024]
    attn_mfma<true><<<2048, 256, 0, stream>>>(
        qkv_b, qkv_b + 1024, qkv_b + 2048, attn_b, 3072, 3072, SEQ_T);
    // 4. x1 = x + attn @ w_ao + b_ao -> f32   grid 8*64=512
    gemm_mfma<1><<<512, 256, 0, stream>>>(
        attn_b, wt_ao, b_ao, x, x1, ROWS, 1024, 1024, 1024, 8);
    // 5. y2 = LN(x1) -> bf16
    ln_bf16<<<ROWS, 256, 0, stream>>>(x1, ln2_g, ln2_b, y_b);
    // 6. q = y2 @ w_q + b_q -> bf16   grid 512
    gemm_mfma<0><<<512, 256, 0, stream>>>(
        y_b, wt_q, b_q, nullptr, q_b, ROWS, 1024, 1024, 1024, 8);
    // 7. kv = enc @ w_kv + b_kv -> bf16 [2056,2048]   grid 16*17=272
    gemm_mfma<0><<<272, 256, 0, stream>>>(
        enc_b, wt_kv, b_kv, nullptr, kv_b, EROWS, 2048, 1024, 1024, 16);
    // 8. cross attention (MFMA) -> bf16 (reuse attn_b)
    attn_mfma<false><<<2048, 256, 0, stream>>>(
        q_b, kv_b, kv_b + 1024, attn_b, 1024, 2048, SEQ_I);
    // 9. x2 = x1 + cross @ w_co + b_co -> f32   grid 512
    gemm_mfma<1><<<512, 256, 0, stream>>>(
        attn_b, wt_co, b_co, x1, x2, ROWS, 1024, 1024, 1024, 8);
    // 10. y3 = LN(x2) -> bf16
    ln_bf16<<<ROWS, 256, 0, stream>>>(x2, ln3_g, ln3_b, y_b);
    // 11. h = gelu(y3 @ w_fc + b_fc) -> bf16 [8192,4096]   grid 32*64=2048
    gemm_mfma<2><<<2048, 256, 0, stream>>>(
        y_b, wt_fc, b_fc, nullptr, h_b, ROWS, 4096, 1024, 1024, 32);
    // 12. out = x2 + h @ w_mo + b_mo -> f32   grid 512
    gemm_mfma<1><<<512, 256, 0, stream>>>(
        h_b, wt_mo, b_mo, x2, outp, ROWS, 1024, 4096, 4096, 8);
}